// Round 1
// baseline (219.447 us; speedup 1.0000x reference)
//
#include <hip/hip_runtime.h>

#define M_DIM   96
#define IN_DIM  16
#define OUT_DIM 16
#define N_BATCH 4

// out[n,s,i,j,k] = Y0[n,s,i] + Y1[n,s,j] + Y2[n,s,k] + S[n,s] + bias[s]
// where Yb[n,s,t] = sum_d x[n,d,t] * coefs[d,s,b],  S = sum_d (sum_t x[n,d,t]) * coefs[d,s,3]
//
// One block per (n,s,i) plane: compute the tiny Y vectors in LDS, then stream
// the 96x96 plane out as coalesced float4 stores. Write-bandwidth bound.
__global__ __launch_bounds__(256) void eq13_kernel(
    const float* __restrict__ x,      // (N, IN_DIM, M)
    const float* __restrict__ coefs,  // (IN_DIM, OUT_DIM, 4)
    const float* __restrict__ bias,   // (OUT_DIM)
    float4* __restrict__ out4)        // (N, OUT_DIM, M, M, M) viewed as float4
{
    __shared__ float s_y0[M_DIM];
    __shared__ float s_y1[M_DIM];
    __shared__ __align__(16) float s_y2[M_DIM];
    __shared__ float s_red[M_DIM];
    __shared__ float s_S;

    const int bid = blockIdx.x;          // 0 .. N*OUT*M-1
    const int ns  = bid / M_DIM;         // (n*OUT + s)
    const int i   = bid - ns * M_DIM;
    const int n   = ns >> 4;
    const int s   = ns & 15;
    const int t   = threadIdx.x;

    if (t < M_DIM) {
        float y0 = 0.f, y1 = 0.f, y2 = 0.f, y3 = 0.f;
        const float* xb = x + (size_t)n * IN_DIM * M_DIM + t;
        const float* cb = coefs + s * 4;
        #pragma unroll
        for (int d = 0; d < IN_DIM; ++d) {
            float  xv = xb[d * M_DIM];
            float4 c4 = *(const float4*)(cb + d * OUT_DIM * 4);  // c[d][s][0..3], 16B aligned
            y0 = fmaf(xv, c4.x, y0);
            y1 = fmaf(xv, c4.y, y1);
            y2 = fmaf(xv, c4.z, y2);
            y3 = fmaf(xv, c4.w, y3);
        }
        s_y0[t]  = y0;
        s_y1[t]  = y1;
        s_y2[t]  = y2;
        s_red[t] = y3;
    }
    __syncthreads();

    if (t == 0) {
        float ss = 0.f;
        for (int q = 0; q < M_DIM; ++q) ss += s_red[q];
        s_S = ss + bias[s];
    }
    __syncthreads();

    const float  base = s_y0[i] + s_S;
    const float4* y2v = (const float4*)s_y2;   // 24 float4
    float4* dst = out4 + (size_t)bid * (M_DIM * M_DIM / 4);   // 2304 float4 per plane

    // 2304 float4 per plane = 9 iterations x 256 threads, consecutive lanes ->
    // consecutive 16B stores (perfectly coalesced).
    #pragma unroll
    for (int it = 0; it < 9; ++it) {
        int   c  = t + it * 256;       // 0 .. 2303
        int   j  = c / 24;             // row within plane (0..95)
        int   kq = c - j * 24;         // float4 index along k (0..23)
        float v  = base + s_y1[j];
        float4 f = y2v[kq];
        f.x += v; f.y += v; f.z += v; f.w += v;
        dst[c] = f;
    }
}

extern "C" void kernel_launch(void* const* d_in, const int* in_sizes, int n_in,
                              void* d_out, int out_size, void* d_ws, size_t ws_size,
                              hipStream_t stream) {
    const float* x     = (const float*)d_in[0];
    const float* coefs = (const float*)d_in[1];
    const float* bias  = (const float*)d_in[2];
    float4* out4 = (float4*)d_out;

    const int grid = N_BATCH * OUT_DIM * M_DIM;   // 6144 blocks
    eq13_kernel<<<grid, 256, 0, stream>>>(x, coefs, bias, out4);
}